// Round 1
// baseline (6118.319 us; speedup 1.0000x reference)
//
#include <hip/hip_runtime.h>
#include <stdint.h>

// ---- problem constants (from setup_inputs) ----
static constexpr int NV   = 80000;    // voxels per scale
static constexpr int NPT  = 240000;   // points N
static constexpr int NIMG = 60000;    // B*M image-projected points
static constexpr int Hh   = 64;
static constexpr int Cc   = 20;
static constexpr int NPp  = 120000;   // N per batch
static constexpr int Mm   = 30000;
static constexpr int P3D  = 131072;   // pow2 pad of NV
static constexpr int P2D  = 65536;    // pow2 pad of NIMG
#define BN_EPS 1e-5f

// ================= small helpers =================
__device__ __forceinline__ float waveReduce(float v) {
  #pragma unroll
  for (int o = 32; o > 0; o >>= 1) v += __shfl_down(v, o);
  return v;
}

// ================= gather index =================
__global__ void k_idx(const int* __restrict__ ci, const int* __restrict__ p2img,
                      int* __restrict__ idx) {
  int i = blockIdx.x * blockDim.x + threadIdx.x;
  if (i >= NIMG) return;
  int b = (i >= Mm) ? 1 : 0;                 // B=2, contiguous batch blocks
  idx[i] = ci[b * NPp + p2img[i]];
}

// ================= voxel label vote =================
__global__ void k_counts(const int* __restrict__ ci, const int* __restrict__ labels,
                         int* __restrict__ counts) {
  int i = blockIdx.x * blockDim.x + threadIdx.x;
  if (i >= NPT) return;
  atomicAdd(&counts[(size_t)ci[i] * Cc + labels[i]], 1);
}

__global__ void k_voxlab(const int* __restrict__ counts, int* __restrict__ voxlab) {
  int v = blockIdx.x * blockDim.x + threadIdx.x;
  if (v >= NV) return;
  const int* c = counts + (size_t)v * Cc;
  int best = c[0], arg = 0;
  #pragma unroll
  for (int k = 1; k < Cc; k++) if (c[k] > best) { best = c[k]; arg = k; }  // first-max
  voxlab[v] = arg;
}

// ================= MLP: relu(x@W1+b1)@W2+b2, hidden=128, out=20 =================
// wave-per-row; lane j owns hidden units j and j+64.
template<int D, bool STG>
__global__ void k_mlp2(const float* __restrict__ X, int ldx, int offx, int rows,
                       const float* __restrict__ W1, const float* __restrict__ B1,
                       const float* __restrict__ W2, const float* __restrict__ B2,
                       float* __restrict__ Out) {
  extern __shared__ float sm[];
  float* sw2 = sm;                 // 128*20
  float* sw1 = sm + 2560;          // D*128 when STG
  for (int t = threadIdx.x; t < 2560; t += blockDim.x) sw2[t] = W2[t];
  if (STG) for (int t = threadIdx.x; t < D * 128; t += blockDim.x) sw1[t] = W1[t];
  __syncthreads();
  int lane = threadIdx.x & 63;
  int wid  = (blockIdx.x * blockDim.x + threadIdx.x) >> 6;
  int nw   = (gridDim.x * blockDim.x) >> 6;
  float b1a = B1[lane], b1b = B1[64 + lane];
  for (int row = wid; row < rows; row += nw) {
    const float* xr = X + (size_t)row * ldx + offx;
    float x0 = xr[lane];
    float x1 = (D == 128) ? xr[64 + lane] : 0.f;
    float h0 = b1a, h1 = b1b;
    #pragma unroll
    for (int k = 0; k < 64; k++) {
      float xk = __shfl(x0, k);
      const float* wr = STG ? (sw1 + k * 128) : (W1 + k * 128);
      h0 = fmaf(xk, wr[lane], h0);
      h1 = fmaf(xk, wr[64 + lane], h1);
    }
    if (D == 128) {
      #pragma unroll
      for (int k = 0; k < 64; k++) {
        float xk = __shfl(x1, k);
        const float* wr = STG ? (sw1 + (64 + k) * 128) : (W1 + (64 + k) * 128);
        h0 = fmaf(xk, wr[lane], h0);
        h1 = fmaf(xk, wr[64 + lane], h1);
      }
    }
    h0 = fmaxf(h0, 0.f); h1 = fmaxf(h1, 0.f);
    for (int c = 0; c < Cc; c++) {
      float pc = h0 * sw2[lane * Cc + c] + h1 * sw2[(64 + lane) * Cc + c];
      pc = waveReduce(pc);
      if (lane == 0) Out[(size_t)row * Cc + c] = pc + B2[c];
    }
  }
}

// ================= cross-entropy (mean), accumulated scaled =================
__global__ void k_ce(const float* __restrict__ logits, const int* __restrict__ lab,
                     int n, float scale, float* __restrict__ lossAcc) {
  int i = blockIdx.x * blockDim.x + threadIdx.x;
  float val = 0.f;
  if (i < n) {
    const float* l = logits + (size_t)i * Cc;
    float m = l[0];
    #pragma unroll
    for (int c = 1; c < Cc; c++) m = fmaxf(m, l[c]);
    float se = 0.f;
    #pragma unroll
    for (int c = 0; c < Cc; c++) se += expf(l[c] - m);
    val = -(l[lab[i]] - m - logf(se));
  }
  val = waveReduce(val);
  __shared__ float sh[4];
  int lane = threadIdx.x & 63, w = threadIdx.x >> 6;
  if (lane == 0) sh[w] = val;
  __syncthreads();
  if (threadIdx.x == 0) atomicAdd(lossAcc, (sh[0] + sh[1] + sh[2] + sh[3]) * scale);
}

// ================= Lovász: fill sort items =================
// item = (bits(err) & ~1) | fg  -- fp32 err >= 0 so bits are order-monotone.
// pads (i>=n): item 0 (err=0, fg=0) => exactly neutral to the loss.
__global__ void k_lov_fill(const float* __restrict__ logits, const int* __restrict__ lab,
                           uint32_t* __restrict__ buf, int n, int P) {
  int i = blockIdx.x * blockDim.x + threadIdx.x;
  if (i >= P) return;
  if (i >= n) {
    for (int c = 0; c < Cc; c++) buf[(size_t)c * P + i] = 0u;
    return;
  }
  const float* l = logits + (size_t)i * Cc;
  float m = l[0];
  #pragma unroll
  for (int c = 1; c < Cc; c++) m = fmaxf(m, l[c]);
  float ex[Cc]; float se = 0.f;
  #pragma unroll
  for (int c = 0; c < Cc; c++) { ex[c] = expf(l[c] - m); se += ex[c]; }
  float inv = 1.f / se;
  int lb = lab[i];
  #pragma unroll
  for (int c = 0; c < Cc; c++) {
    float prob = ex[c] * inv;
    int fg = (c == lb) ? 1 : 0;
    float err = fg ? (1.f - prob) : prob;
    err = fmaxf(err, 0.f);
    uint32_t key = __float_as_uint(err);
    buf[(size_t)c * P + i] = (key & 0xFFFFFFFEu) | (uint32_t)fg;
  }
}

// ================= bitonic sort (descending), per-P segment =================
__global__ void k_bitonic_global(uint32_t* __restrict__ buf, int P, int j, int k) {
  int t = blockIdx.x * blockDim.x + threadIdx.x;     // one pair per thread
  int halfP = P >> 1;
  int seg = t / halfP;
  int tt  = t - seg * halfP;
  int jm1 = j - 1;
  int i = ((tt & ~jm1) << 1) | (tt & jm1);
  size_t base = (size_t)seg * P;
  uint32_t a = buf[base + i], b = buf[base + i + j];
  bool descend = ((i & k) == 0);
  if ((a < b) == descend) { buf[base + i] = b; buf[base + i + j] = a; }
}

// chunk=2048 in LDS; does stages k=kBegin..kEnd with j<=1024 fused.
__global__ void __launch_bounds__(1024)
k_bitonic_fused(uint32_t* __restrict__ buf, int P, int kBegin, int kEnd) {
  __shared__ uint32_t sh[2048];
  int t = threadIdx.x;
  size_t chunkStart = (size_t)blockIdx.x * 2048;
  int segBase = (int)(chunkStart % (size_t)P);       // segment-local chunk offset
  sh[t]        = buf[chunkStart + t];
  sh[t + 1024] = buf[chunkStart + 1024 + t];
  for (int k = kBegin; k <= kEnd; k <<= 1) {
    int j0 = (k >> 1) < 1024 ? (k >> 1) : 1024;
    for (int j = j0; j >= 1; j >>= 1) {
      __syncthreads();
      int jm1 = j - 1;
      int i = ((t & ~jm1) << 1) | (t & jm1);
      int ixj = i + j;
      bool descend = (((segBase + i) & k) == 0);
      uint32_t a = sh[i], b = sh[ixj];
      if ((a < b) == descend) { sh[i] = b; sh[ixj] = a; }
    }
  }
  __syncthreads();
  buf[chunkStart + t]        = sh[t];
  buf[chunkStart + 1024 + t] = sh[t + 1024];
}

// ================= Lovász: segmented scan of fg + contributions =================
__global__ void k_lov_chunksum(const uint32_t* __restrict__ buf, int* __restrict__ chunkSums) {
  int t = threadIdx.x;                                // 256
  size_t base = (size_t)blockIdx.x * 1024;
  int v = (int)(buf[base + t] & 1) + (int)(buf[base + t + 256] & 1)
        + (int)(buf[base + t + 512] & 1) + (int)(buf[base + t + 768] & 1);
  #pragma unroll
  for (int o = 32; o > 0; o >>= 1) v += __shfl_down(v, o);
  __shared__ int sh[4];
  int lane = t & 63, w = t >> 6;
  if (lane == 0) sh[w] = v;
  __syncthreads();
  if (t == 0) chunkSums[blockIdx.x] = sh[0] + sh[1] + sh[2] + sh[3];
}

__global__ void k_lov_scan(const int* __restrict__ chunkSums, int* __restrict__ chunkOffs,
                           int* __restrict__ gtsArr, int nch) {
  __shared__ int sh[128];
  int t = threadIdx.x;                                // 128
  int v = (t < nch) ? chunkSums[blockIdx.x * nch + t] : 0;
  sh[t] = v;
  __syncthreads();
  for (int o = 1; o < 128; o <<= 1) {
    int a = (t >= o) ? sh[t - o] : 0;
    __syncthreads();
    sh[t] += a;
    __syncthreads();
  }
  if (t < nch) chunkOffs[blockIdx.x * nch + t] = sh[t] - v;   // exclusive
  if (t == nch - 1) gtsArr[blockIdx.x] = sh[t];               // total fg
}

__global__ void __launch_bounds__(1024)
k_lov_contrib(const uint32_t* __restrict__ buf, const int* __restrict__ chunkOffs,
              const int* __restrict__ gtsArr, float* __restrict__ lossesC,
              int P, int nch) {
  int t = threadIdx.x;                                // 1024
  size_t g = (size_t)blockIdx.x * 1024 + t;
  int cls   = blockIdx.x / nch;
  int chunk = blockIdx.x - cls * nch;
  int iseg  = chunk * 1024 + t;
  uint32_t item = buf[g];
  int fg = item & 1;
  float e = __uint_as_float(item & 0xFFFFFFFEu);
  unsigned long long mask = __ballot(fg);
  int lane = t & 63, wave = t >> 6;
  unsigned long long le = (~0ull) >> (63 - lane);
  int wIncl = __popcll(mask & le);
  __shared__ int wsum[16];
  if (lane == 63) wsum[wave] = wIncl;                 // wave total
  __syncthreads();
  if (t == 0) { int run = 0; for (int w = 0; w < 16; w++) { int v = wsum[w]; wsum[w] = run; run += v; } }
  __syncthreads();
  float Fi  = (float)(chunkOffs[blockIdx.x] + wsum[wave] + wIncl);  // inclusive F
  float gts = (float)gtsArr[cls];
  float ip1 = (float)(iseg + 1);
  float Jc = 1.f - (gts - Fi) / (gts + ip1 - Fi);
  float Jp = 0.f;
  if (iseg > 0) {
    float Fp = Fi - (float)fg;
    Jp = 1.f - (gts - Fp) / (gts + (ip1 - 1.f) - Fp);
  }
  float contrib = e * (Jc - Jp);
  contrib = waveReduce(contrib);
  __shared__ float bs[16];
  if (lane == 0) bs[wave] = contrib;
  __syncthreads();
  if (t == 0) { float s = 0.f; for (int w = 0; w < 16; w++) s += bs[w]; atomicAdd(&lossesC[cls], s); }
}

__global__ void k_lov_combine(const float* __restrict__ lossesC, const int* __restrict__ gtsArr,
                              float* __restrict__ lossAcc, float coef) {
  float s = 0.f; int np = 0;
  for (int c = 0; c < Cc; c++) if (gtsArr[c] > 0) { s += lossesC[c]; np++; }
  atomicAdd(lossAcc, coef * s / (float)(np > 0 ? np : 1));
}

// ================= attention weights =================
__global__ void k_att(const float* __restrict__ pts, const int* __restrict__ idx,
                      const float* __restrict__ img,
                      const float* __restrict__ fc1w, const float* __restrict__ fc1b,
                      const float* __restrict__ fc2w, const float* __restrict__ fc2b,
                      const float* __restrict__ fc3w, const float* __restrict__ fc3b,
                      float* __restrict__ attw) {
  int i = blockIdx.x * blockDim.x + threadIdx.x;
  if (i >= NIMG) return;
  const float* p = pts + (size_t)idx[i] * Hh;
  const float* v = img + (size_t)i * Hh;
  float l0 = fc3b[0], l1 = fc3b[1];
  float a[16];
  #pragma unroll
  for (int j = 0; j < 16; j++) a[j] = fc1b[j];
  for (int k = 0; k < 64; k++) {
    float pk = p[k];
    #pragma unroll
    for (int j = 0; j < 16; j++) a[j] = fmaf(pk, fc1w[k * 16 + j], a[j]);
  }
  #pragma unroll
  for (int j = 0; j < 16; j++) { l0 = fmaf(a[j], fc3w[j * 2], l0); l1 = fmaf(a[j], fc3w[j * 2 + 1], l1); }
  #pragma unroll
  for (int j = 0; j < 16; j++) a[j] = fc2b[j];
  for (int k = 0; k < 64; k++) {
    float vk = v[k];
    #pragma unroll
    for (int j = 0; j < 16; j++) a[j] = fmaf(vk, fc2w[k * 16 + j], a[j]);
  }
  #pragma unroll
  for (int j = 0; j < 16; j++) { l0 = fmaf(a[j], fc3w[(16 + j) * 2], l0); l1 = fmaf(a[j], fc3w[(16 + j) * 2 + 1], l1); }
  attw[i * 2]     = 1.f / (1.f + expf(-l0));
  attw[i * 2 + 1] = 1.f / (1.f + expf(-l1));
}

// ================= y1/y2 GEMM (64x64) + column sums/sumsq =================
__global__ void k_gemm_y(const float* __restrict__ pts, const int* __restrict__ idx,
                         const float* __restrict__ img,
                         const float* __restrict__ c1w, const float* __restrict__ c1b,
                         const float* __restrict__ c2w, const float* __restrict__ c2b,
                         float* __restrict__ y1, float* __restrict__ y2,
                         float* __restrict__ colstats) {
  __shared__ float s1[64 * 64], s2[64 * 64];
  __shared__ float cs[4][64];
  int t = threadIdx.x;                                // 256
  for (int i = t; i < 4096; i += 256) { s1[i] = c1w[i]; s2[i] = c2w[i]; }
  if (t < 64) { cs[0][t] = 0.f; cs[1][t] = 0.f; cs[2][t] = 0.f; cs[3][t] = 0.f; }
  __syncthreads();
  int lane = t & 63;
  int wid  = (blockIdx.x * 256 + t) >> 6;
  int nw   = (gridDim.x * 256) >> 6;
  float b1 = c1b[lane], b2 = c2b[lane];
  float a1 = 0.f, q1 = 0.f, a2 = 0.f, q2 = 0.f;
  for (int row = wid; row < NIMG; row += nw) {
    float pv = pts[(size_t)idx[row] * Hh + lane];
    float vv = img[(size_t)row * Hh + lane];
    float acc1 = b1, acc2 = b2;
    #pragma unroll
    for (int k = 0; k < 64; k++) {
      float pk = __shfl(pv, k), vk = __shfl(vv, k);
      acc1 = fmaf(pk, s1[k * 64 + lane], acc1);
      acc2 = fmaf(vk, s2[k * 64 + lane], acc2);
    }
    y1[(size_t)row * Hh + lane] = acc1;
    y2[(size_t)row * Hh + lane] = acc2;
    a1 += acc1; q1 = fmaf(acc1, acc1, q1);
    a2 += acc2; q2 = fmaf(acc2, acc2, q2);
  }
  atomicAdd(&cs[0][lane], a1); atomicAdd(&cs[1][lane], q1);
  atomicAdd(&cs[2][lane], a2); atomicAdd(&cs[3][lane], q2);
  __syncthreads();
  if (t < 64) {
    atomicAdd(&colstats[t],       cs[0][t]);
    atomicAdd(&colstats[64 + t],  cs[1][t]);
    atomicAdd(&colstats[128 + t], cs[2][t]);
    atomicAdd(&colstats[192 + t], cs[3][t]);
  }
}

__global__ void k_colfinal(const float* __restrict__ colstats,
                           const float* __restrict__ g1, const float* __restrict__ be1,
                           const float* __restrict__ g2, const float* __restrict__ be2,
                           float* __restrict__ bnpar) {
  int j = threadIdx.x;                                // 64
  float n = (float)NIMG;
  float mu1 = colstats[j] / n;
  float var1 = colstats[64 + j] / n - mu1 * mu1;
  float a1 = g1[j] / sqrtf(var1 + BN_EPS);
  bnpar[j] = a1; bnpar[64 + j] = be1[j] - mu1 * a1;
  float mu2 = colstats[128 + j] / n;
  float var2 = colstats[192 + j] / n - mu2 * mu2;
  float a2 = g2[j] / sqrtf(var2 + BN_EPS);
  bnpar[128 + j] = a2; bnpar[192 + j] = be2[j] - mu2 * a2;
}

__global__ void k_fuse(const float* __restrict__ y1, const float* __restrict__ y2,
                       const float* __restrict__ attw, const float* __restrict__ bnpar,
                       float* __restrict__ feats, int s) {
  int g = blockIdx.x * blockDim.x + threadIdx.x;
  if (g >= NIMG * Hh) return;
  int i = g >> 6, j = g & 63;
  float z1 = fmaxf(fmaf(y1[g], bnpar[j],       bnpar[64 + j]),  0.f);
  float z2 = fmaxf(fmaf(y2[g], bnpar[128 + j], bnpar[192 + j]), 0.f);
  feats[(size_t)i * 128 + s * 64 + j] = z1 * attw[i * 2] + z2 * attw[i * 2 + 1];
}

// ================= KL(log_softmax(pts_pred) || softmax(fuse_pred)) =================
__global__ void k_kl(const float* __restrict__ fusepred, const float* __restrict__ pred3d,
                     const int* __restrict__ idx, int n, float scale, float* __restrict__ lossAcc) {
  int i = blockIdx.x * blockDim.x + threadIdx.x;
  float val = 0.f;
  if (i < n) {
    const float* f = fusepred + (size_t)i * Cc;
    const float* q = pred3d + (size_t)idx[i] * Cc;
    float mf = f[0], mq = q[0];
    #pragma unroll
    for (int c = 1; c < Cc; c++) { mf = fmaxf(mf, f[c]); mq = fmaxf(mq, q[c]); }
    float sf = 0.f, sq = 0.f;
    #pragma unroll
    for (int c = 0; c < Cc; c++) { sf += expf(f[c] - mf); sq += expf(q[c] - mq); }
    float lsf = logf(sf), lsq = logf(sq);
    #pragma unroll
    for (int c = 0; c < Cc; c++) {
      float lf = f[c] - mf - lsf;
      float pf = expf(lf);
      float lq = q[c] - mq - lsq;
      val += pf * (lf - lq);
    }
  }
  val = waveReduce(val);
  __shared__ float sh[4];
  int lane = threadIdx.x & 63, w = threadIdx.x >> 6;
  if (lane == 0) sh[w] = val;
  __syncthreads();
  if (threadIdx.x == 0) atomicAdd(lossAcc, (sh[0] + sh[1] + sh[2] + sh[3]) * scale);
}

__global__ void k_final(const float* __restrict__ lossAcc, float* __restrict__ out) {
  out[0] = lossAcc[0];
}

// ================= host-side drivers =================
static void run_sort(uint32_t* buf, int P, hipStream_t stream) {
  int total = Cc * P;
  int fusedBlocks = total / 2048;
  k_bitonic_fused<<<fusedBlocks, 1024, 0, stream>>>(buf, P, 2, 2048);
  for (int k = 4096; k <= P; k <<= 1) {
    for (int j = k >> 1; j >= 2048; j >>= 1)
      k_bitonic_global<<<(total / 2) / 256, 256, 0, stream>>>(buf, P, j, k);
    k_bitonic_fused<<<fusedBlocks, 1024, 0, stream>>>(buf, P, k, k);
  }
}

static void run_lovasz(const float* logits, const int* labels, int n, int P, float coef,
                       uint32_t* buf, int* chunkSums, int* chunkOffs,
                       float* lossesC, int* gtsArr, float* lossAcc, hipStream_t stream) {
  hipMemsetAsync(lossesC, 0, Cc * sizeof(float), stream);
  k_lov_fill<<<P / 256, 256, 0, stream>>>(logits, labels, buf, n, P);
  run_sort(buf, P, stream);
  int nch = P / 1024;
  k_lov_chunksum<<<Cc * nch, 256, 0, stream>>>(buf, chunkSums);
  k_lov_scan<<<Cc, 128, 0, stream>>>(chunkSums, chunkOffs, gtsArr, nch);
  k_lov_contrib<<<Cc * nch, 1024, 0, stream>>>(buf, chunkOffs, gtsArr, lossesC, P, nch);
  k_lov_combine<<<1, 1, 0, stream>>>(lossesC, gtsArr, lossAcc, coef);
}

template<int D, bool STG>
static void launch_mlp(const float* X, int ldx, int offx, int rows,
                       const float* W1, const float* B1, const float* W2, const float* B2,
                       float* Out, hipStream_t stream) {
  size_t shb = (2560 + (STG ? D * 128 : 0)) * sizeof(float);
  k_mlp2<D, STG><<<512, 256, shb, stream>>>(X, ldx, offx, rows, W1, B1, W2, B2, Out);
}

extern "C" void kernel_launch(void* const* d_in, const int* in_sizes, int n_in,
                              void* d_out, int out_size, void* d_ws, size_t ws_size,
                              hipStream_t stream) {
  const float* img_feat = (const float*)d_in[0];
  const float* pts_feat = (const float*)d_in[1];
  const int* coors_inv  = (const int*)d_in[2];
  const int* labels     = (const int*)d_in[3];
  const int* img_label  = (const int*)d_in[4];
  const int* p2img      = (const int*)d_in[5];
  const float* w3a = (const float*)d_in[6];
  const float* b3a = (const float*)d_in[7];
  const float* w3b = (const float*)d_in[8];
  const float* b3b = (const float*)d_in[9];
  const float* wfa = (const float*)d_in[10];
  const float* bfa = (const float*)d_in[11];
  const float* wfb = (const float*)d_in[12];
  const float* bfb = (const float*)d_in[13];
  const float* fc1w = (const float*)d_in[14];
  const float* fc1b = (const float*)d_in[15];
  const float* fc2w = (const float*)d_in[16];
  const float* fc2b = (const float*)d_in[17];
  const float* fc3w = (const float*)d_in[18];
  const float* fc3b = (const float*)d_in[19];
  const float* c1w  = (const float*)d_in[20];
  const float* c1b  = (const float*)d_in[21];
  const float* bn1g = (const float*)d_in[22];
  const float* bn1b = (const float*)d_in[23];
  const float* c2w  = (const float*)d_in[24];
  const float* c2b  = (const float*)d_in[25];
  const float* bn2g = (const float*)d_in[26];
  const float* bn2b = (const float*)d_in[27];
  const float* clw1 = (const float*)d_in[28];
  const float* clb1 = (const float*)d_in[29];
  const float* clw2 = (const float*)d_in[30];
  const float* clb2 = (const float*)d_in[31];
  (void)in_sizes; (void)n_in; (void)out_size; (void)ws_size;

  // ---- workspace layout (time-disjoint overlays; ~75 MB total) ----
  char* ws = (char*)d_ws;
  size_t off = 0;
  auto alloc = [&](size_t bytes) { void* p = ws + off; off += (bytes + 255) & ~(size_t)255; return p; };
  float* feats  = (float*)alloc((size_t)NIMG * 128 * 4);   // persistent (concat of fuse[s])
  float* pred3d = (float*)alloc((size_t)NV * Cc * 4);
  int*   voxlab = (int*)  alloc((size_t)NV * 4);
  int*   idx    = (int*)  alloc((size_t)NIMG * 4);
  // regionA: y1+y2 (live gemm_y..fuse)  OVERLAYS  sortbuf (live lovasz only)
  char* regionA = (char*)alloc((size_t)NIMG * Hh * 4 * 2);  // 30.72MB >= 20*P3D*4
  float* y1 = (float*)regionA;
  float* y2 = (float*)(regionA + (size_t)NIMG * Hh * 4);
  uint32_t* sortbuf = (uint32_t*)regionA;
  // regionB: counts (live early)  OVERLAYS  attw+fusepred (live late)
  char* regionB = (char*)alloc((size_t)NV * Cc * 4);        // 6.4MB >= 0.48+4.8MB
  int*   counts   = (int*)regionB;
  float* attw     = (float*)regionB;
  float* fusepred = (float*)(regionB + (size_t)NIMG * 2 * 4);
  int* chunkSums = (int*)alloc(Cc * 128 * 4);
  int* chunkOffs = (int*)alloc(Cc * 128 * 4);
  float* statsF  = (float*)alloc(4096);
  float* lossAcc  = statsF;             // [0]
  float* lossesC  = statsF + 1;         // [1..21)
  int*   gtsArr   = (int*)(statsF + 21);// 20 ints
  float* colstats = statsF + 64;        // 256 floats
  float* bnpar    = statsF + 320;       // 256 floats

  hipMemsetAsync(statsF, 0, 4096, stream);

  for (int s = 0; s < 2; s++) {
    const float* pf_s = pts_feat + (size_t)s * NV * Hh;
    const float* if_s = img_feat + (size_t)s * NIMG * Hh;
    const int*   ci_s = coors_inv + (size_t)s * NPT;
    hipMemsetAsync(counts, 0, (size_t)NV * Cc * 4, stream);
    hipMemsetAsync(colstats, 0, 256 * 4, stream);
    k_idx<<<(NIMG + 255) / 256, 256, 0, stream>>>(ci_s, p2img, idx);
    // pred3d = mlp2(pts_feat[s])
    launch_mlp<64, true>(pf_s, Hh, 0, NV, w3a + s * 64 * 128, b3a + s * 128,
                         w3b + s * 128 * Cc, b3b + s * Cc, pred3d, stream);
    k_counts<<<(NPT + 255) / 256, 256, 0, stream>>>(ci_s, labels, counts);
    k_voxlab<<<(NV + 255) / 256, 256, 0, stream>>>(counts, voxlab);
    // seg_loss(pred3d, vox_lab), coef 1
    k_ce<<<(NV + 255) / 256, 256, 0, stream>>>(pred3d, voxlab, NV, 1.0f / NV, lossAcc);
    run_lovasz(pred3d, voxlab, NV, P3D, 1.0f, sortbuf, chunkSums, chunkOffs,
               lossesC, gtsArr, lossAcc, stream);
    // attention + fusion
    k_att<<<(NIMG + 255) / 256, 256, 0, stream>>>(pf_s, idx, if_s,
        fc1w + s * 64 * 16, fc1b + s * 16, fc2w + s * 64 * 16, fc2b + s * 16,
        fc3w + s * 64, fc3b + s * 2, attw);
    k_gemm_y<<<512, 256, 0, stream>>>(pf_s, idx, if_s,
        c1w + s * 4096, c1b + s * 64, c2w + s * 4096, c2b + s * 64, y1, y2, colstats);
    k_colfinal<<<1, 64, 0, stream>>>(colstats, bn1g + s * 64, bn1b + s * 64,
                                     bn2g + s * 64, bn2b + s * 64, bnpar);
    k_fuse<<<(NIMG * Hh + 255) / 256, 256, 0, stream>>>(y1, y2, attw, bnpar, feats, s);
    // fuse_pred = mlp2(fuse)
    launch_mlp<64, true>(feats, 128, s * 64, NIMG, wfa + s * 64 * 128, bfa + s * 128,
                         wfb + s * 128 * Cc, bfb + s * Cc, fusepred, stream);
    // seg_loss(fuse_pred, img_label) * 1/S
    k_ce<<<(NIMG + 255) / 256, 256, 0, stream>>>(fusepred, img_label, NIMG, 0.5f / NIMG, lossAcc);
    run_lovasz(fusepred, img_label, NIMG, P2D, 0.5f, sortbuf, chunkSums, chunkOffs,
               lossesC, gtsArr, lossAcc, stream);
    // KL * 0.05/S, mean over NIMG*C elements
    k_kl<<<(NIMG + 255) / 256, 256, 0, stream>>>(fusepred, pred3d, idx, NIMG,
        0.025f / ((float)NIMG * Cc), lossAcc);
  }
  // final classifier on concat feats
  launch_mlp<128, false>(feats, 128, 0, NIMG, clw1, clb1, clw2, clb2, fusepred, stream);
  k_ce<<<(NIMG + 255) / 256, 256, 0, stream>>>(fusepred, img_label, NIMG, 1.0f / NIMG, lossAcc);
  run_lovasz(fusepred, img_label, NIMG, P2D, 1.0f, sortbuf, chunkSums, chunkOffs,
             lossesC, gtsArr, lossAcc, stream);
  k_final<<<1, 1, 0, stream>>>(lossAcc, (float*)d_out);
}

// Round 2
// 1482.236 us; speedup vs baseline: 4.1278x; 4.1278x over previous
//
#include <hip/hip_runtime.h>
#include <stdint.h>

// ---- problem constants (from setup_inputs) ----
static constexpr int NV   = 80000;    // voxels per scale
static constexpr int NPT  = 240000;   // points N
static constexpr int NIMG = 60000;    // B*M image-projected points
static constexpr int Hh   = 64;
static constexpr int Cc   = 20;
static constexpr int NPp  = 120000;   // N per batch
static constexpr int Mm   = 30000;
static constexpr int P3D  = 131072;   // pow2 pad of NV
static constexpr int P2D  = 65536;    // pow2 pad of NIMG
#define BN_EPS 1e-5f

// ================= small helpers =================
__device__ __forceinline__ float waveReduce(float v) {
  #pragma unroll
  for (int o = 32; o > 0; o >>= 1) v += __shfl_down(v, o);
  return v;
}

// ================= gather index =================
__global__ void k_idx(const int* __restrict__ ci, const int* __restrict__ p2img,
                      int* __restrict__ idx) {
  int i = blockIdx.x * blockDim.x + threadIdx.x;
  if (i >= NIMG) return;
  int b = (i >= Mm) ? 1 : 0;                 // B=2, contiguous batch blocks
  idx[i] = ci[b * NPp + p2img[i]];
}

// ================= voxel label vote =================
__global__ void k_counts(const int* __restrict__ ci, const int* __restrict__ labels,
                         int* __restrict__ counts) {
  int i = blockIdx.x * blockDim.x + threadIdx.x;
  if (i >= NPT) return;
  atomicAdd(&counts[(size_t)ci[i] * Cc + labels[i]], 1);
}

__global__ void k_voxlab(const int* __restrict__ counts, int* __restrict__ voxlab) {
  int v = blockIdx.x * blockDim.x + threadIdx.x;
  if (v >= NV) return;
  const int* c = counts + (size_t)v * Cc;
  int best = c[0], arg = 0;
  #pragma unroll
  for (int k = 1; k < Cc; k++) if (c[k] > best) { best = c[k]; arg = k; }  // first-max
  voxlab[v] = arg;
}

// ================= tiled MLP: relu(x@W1+b1)@W2+b2, hidden=128, out=20 =====
// Block = 256 threads, TR rows per block. Layer1: thread = (rg = t>>5) x
// (hg = t&31), computes RPG rows x 4 hidden, W1 via L1 float4. Layer2 via
// LDS hidden tile, 2 rows x 4 classes per unit. No shuffles anywhere.
template<int TR, int D>
__global__ void __launch_bounds__(256)
k_mlp2t(const float* __restrict__ X, int ldx, int offx, int rows,
        const float* __restrict__ W1, const float* __restrict__ B1,
        const float* __restrict__ W2, const float* __restrict__ B2,
        float* __restrict__ Out) {
  constexpr int LDX = D + 1;
  constexpr int RPG = TR / 8;
  __shared__ float sX[TR * LDX];
  __shared__ float sH[TR * 130];
  __shared__ float sW2[128 * 20];
  __shared__ float sB1[128];
  int t = threadIdx.x;
  int r0 = blockIdx.x * TR;
  for (int i = t; i < 2560; i += 256) sW2[i] = W2[i];
  if (t < 128) sB1[t] = B1[t];
  // stage X tile (float4 rows)
  for (int i = t; i < TR * (D / 4); i += 256) {
    int r = i / (D / 4), k4 = (i - r * (D / 4)) * 4;
    int gr = r0 + r;
    float4 v = make_float4(0.f, 0.f, 0.f, 0.f);
    if (gr < rows) v = *(const float4*)(X + (size_t)gr * ldx + offx + k4);
    float* d = sX + r * LDX + k4;
    d[0] = v.x; d[1] = v.y; d[2] = v.z; d[3] = v.w;
  }
  __syncthreads();
  // ---- layer 1 ----
  int hg = t & 31, rg = t >> 5;
  float acc[RPG][4];
  #pragma unroll
  for (int i = 0; i < RPG; i++) {
    acc[i][0] = sB1[hg * 4]; acc[i][1] = sB1[hg * 4 + 1];
    acc[i][2] = sB1[hg * 4 + 2]; acc[i][3] = sB1[hg * 4 + 3];
  }
  for (int k = 0; k < D; k++) {
    float4 b = *(const float4*)(W1 + k * 128 + hg * 4);
    #pragma unroll
    for (int i = 0; i < RPG; i++) {
      float a = sX[(rg * RPG + i) * LDX + k];
      acc[i][0] = fmaf(a, b.x, acc[i][0]);
      acc[i][1] = fmaf(a, b.y, acc[i][1]);
      acc[i][2] = fmaf(a, b.z, acc[i][2]);
      acc[i][3] = fmaf(a, b.w, acc[i][3]);
    }
  }
  #pragma unroll
  for (int i = 0; i < RPG; i++) {
    int r = rg * RPG + i;
    sH[r * 130 + hg * 4]     = fmaxf(acc[i][0], 0.f);
    sH[r * 130 + hg * 4 + 1] = fmaxf(acc[i][1], 0.f);
    sH[r * 130 + hg * 4 + 2] = fmaxf(acc[i][2], 0.f);
    sH[r * 130 + hg * 4 + 3] = fmaxf(acc[i][3], 0.f);
  }
  __syncthreads();
  // ---- layer 2: TR x 20, units = 2 rows x 4 classes ----
  constexpr int NU = (TR / 2) * 5;
  for (int u = t; u < NU; u += 256) {
    int rp = u / 5, cc = u - rp * 5;
    int r = rp * 2, c = cc * 4;
    float o0[4], o1[4];
    #pragma unroll
    for (int j = 0; j < 4; j++) { o0[j] = B2[c + j]; o1[j] = o0[j]; }
    for (int k = 0; k < 128; k++) {
      float h0 = sH[r * 130 + k];
      float h1 = sH[(r + 1) * 130 + k];
      float4 w = *(const float4*)(sW2 + k * 20 + c);
      o0[0] = fmaf(h0, w.x, o0[0]); o0[1] = fmaf(h0, w.y, o0[1]);
      o0[2] = fmaf(h0, w.z, o0[2]); o0[3] = fmaf(h0, w.w, o0[3]);
      o1[0] = fmaf(h1, w.x, o1[0]); o1[1] = fmaf(h1, w.y, o1[1]);
      o1[2] = fmaf(h1, w.z, o1[2]); o1[3] = fmaf(h1, w.w, o1[3]);
    }
    int gr = r0 + r;
    if (gr < rows) {
      #pragma unroll
      for (int j = 0; j < 4; j++) Out[(size_t)gr * Cc + c + j] = o0[j];
    }
    if (gr + 1 < rows) {
      #pragma unroll
      for (int j = 0; j < 4; j++) Out[(size_t)(gr + 1) * Cc + c + j] = o1[j];
    }
  }
}

// ================= fused gather + y1/y2 GEMM + BN-stats + attention =========
__global__ void __launch_bounds__(256)
k_gemm_att(const float* __restrict__ pts, const int* __restrict__ idx,
           const float* __restrict__ img,
           const float* __restrict__ c1w, const float* __restrict__ c1b,
           const float* __restrict__ c2w, const float* __restrict__ c2b,
           const float* __restrict__ fc1w, const float* __restrict__ fc1b,
           const float* __restrict__ fc2w, const float* __restrict__ fc2b,
           const float* __restrict__ fc3w, const float* __restrict__ fc3b,
           float* __restrict__ y1, float* __restrict__ y2,
           float* __restrict__ attw, float* __restrict__ colstats) {
  __shared__ float sP[64 * 65], sV[64 * 65];
  __shared__ float cs[4][64];
  int t = threadIdx.x;
  int r0 = blockIdx.x * 64;
  if (t < 64) { cs[0][t] = 0.f; cs[1][t] = 0.f; cs[2][t] = 0.f; cs[3][t] = 0.f; }
  // stage gathered p rows and v rows (float4)
  for (int i = t; i < 64 * 16; i += 256) {
    int r = i >> 4, k4 = (i & 15) * 4;
    int gr = r0 + r;
    float4 vp = make_float4(0.f, 0.f, 0.f, 0.f), vv = vp;
    if (gr < NIMG) {
      vp = *(const float4*)(pts + (size_t)idx[gr] * Hh + k4);
      vv = *(const float4*)(img + (size_t)gr * Hh + k4);
    }
    float* dp = sP + r * 65 + k4; float* dv = sV + r * 65 + k4;
    dp[0] = vp.x; dp[1] = vp.y; dp[2] = vp.z; dp[3] = vp.w;
    dv[0] = vv.x; dv[1] = vv.y; dv[2] = vv.z; dv[3] = vv.w;
  }
  __syncthreads();
  // GEMM: half 0 -> y1 = sP @ c1w, half 1 -> y2 = sV @ c2w
  int half = t >> 7, tl = t & 127;
  int rg = tl >> 4, cg = tl & 15;          // 8 rows x 4 cols per thread
  const float* src = half ? sV : sP;
  const float* W   = half ? c2w : c1w;
  const float* Bb  = half ? c2b : c1b;
  float acc[8][4];
  #pragma unroll
  for (int i = 0; i < 8; i++) {
    acc[i][0] = Bb[cg * 4]; acc[i][1] = Bb[cg * 4 + 1];
    acc[i][2] = Bb[cg * 4 + 2]; acc[i][3] = Bb[cg * 4 + 3];
  }
  for (int k = 0; k < 64; k++) {
    float4 b = *(const float4*)(W + k * 64 + cg * 4);
    #pragma unroll
    for (int i = 0; i < 8; i++) {
      float a = src[(rg * 8 + i) * 65 + k];
      acc[i][0] = fmaf(a, b.x, acc[i][0]);
      acc[i][1] = fmaf(a, b.y, acc[i][1]);
      acc[i][2] = fmaf(a, b.z, acc[i][2]);
      acc[i][3] = fmaf(a, b.w, acc[i][3]);
    }
  }
  float* Y = half ? y2 : y1;
  int so = half ? 2 : 0;
  float s0 = 0.f, s1 = 0.f, s2 = 0.f, s3 = 0.f;
  float q0 = 0.f, q1 = 0.f, q2 = 0.f, q3 = 0.f;
  #pragma unroll
  for (int i = 0; i < 8; i++) {
    int gr = r0 + rg * 8 + i;
    if (gr < NIMG) {
      *(float4*)(Y + (size_t)gr * Hh + cg * 4) =
          make_float4(acc[i][0], acc[i][1], acc[i][2], acc[i][3]);
      s0 += acc[i][0]; q0 = fmaf(acc[i][0], acc[i][0], q0);
      s1 += acc[i][1]; q1 = fmaf(acc[i][1], acc[i][1], q1);
      s2 += acc[i][2]; q2 = fmaf(acc[i][2], acc[i][2], q2);
      s3 += acc[i][3]; q3 = fmaf(acc[i][3], acc[i][3], q3);
    }
  }
  atomicAdd(&cs[so][cg * 4], s0);     atomicAdd(&cs[so][cg * 4 + 1], s1);
  atomicAdd(&cs[so][cg * 4 + 2], s2); atomicAdd(&cs[so][cg * 4 + 3], s3);
  atomicAdd(&cs[so + 1][cg * 4], q0);     atomicAdd(&cs[so + 1][cg * 4 + 1], q1);
  atomicAdd(&cs[so + 1][cg * 4 + 2], q2); atomicAdd(&cs[so + 1][cg * 4 + 3], q3);
  // attention for this tile's rows (threads 0..63)
  if (t < 64 && r0 + t < NIMG) {
    const float* p = sP + t * 65;
    const float* v = sV + t * 65;
    float l0 = fc3b[0], l1 = fc3b[1];
    float a[16];
    #pragma unroll
    for (int j = 0; j < 16; j++) a[j] = fc1b[j];
    for (int k = 0; k < 64; k++) {
      float pk = p[k];
      #pragma unroll
      for (int j = 0; j < 16; j++) a[j] = fmaf(pk, fc1w[k * 16 + j], a[j]);
    }
    #pragma unroll
    for (int j = 0; j < 16; j++) { l0 = fmaf(a[j], fc3w[j * 2], l0); l1 = fmaf(a[j], fc3w[j * 2 + 1], l1); }
    #pragma unroll
    for (int j = 0; j < 16; j++) a[j] = fc2b[j];
    for (int k = 0; k < 64; k++) {
      float vk = v[k];
      #pragma unroll
      for (int j = 0; j < 16; j++) a[j] = fmaf(vk, fc2w[k * 16 + j], a[j]);
    }
    #pragma unroll
    for (int j = 0; j < 16; j++) { l0 = fmaf(a[j], fc3w[(16 + j) * 2], l0); l1 = fmaf(a[j], fc3w[(16 + j) * 2 + 1], l1); }
    attw[(r0 + t) * 2]     = 1.f / (1.f + expf(-l0));
    attw[(r0 + t) * 2 + 1] = 1.f / (1.f + expf(-l1));
  }
  __syncthreads();
  if (t < 64) {
    atomicAdd(&colstats[t],       cs[0][t]);
    atomicAdd(&colstats[64 + t],  cs[1][t]);
    atomicAdd(&colstats[128 + t], cs[2][t]);
    atomicAdd(&colstats[192 + t], cs[3][t]);
  }
}

// ================= cross-entropy (mean), accumulated scaled =================
__global__ void k_ce(const float* __restrict__ logits, const int* __restrict__ lab,
                     int n, float scale, float* __restrict__ lossAcc) {
  int i = blockIdx.x * blockDim.x + threadIdx.x;
  float val = 0.f;
  if (i < n) {
    const float* l = logits + (size_t)i * Cc;
    float m = l[0];
    #pragma unroll
    for (int c = 1; c < Cc; c++) m = fmaxf(m, l[c]);
    float se = 0.f;
    #pragma unroll
    for (int c = 0; c < Cc; c++) se += expf(l[c] - m);
    val = -(l[lab[i]] - m - logf(se));
  }
  val = waveReduce(val);
  __shared__ float sh[4];
  int lane = threadIdx.x & 63, w = threadIdx.x >> 6;
  if (lane == 0) sh[w] = val;
  __syncthreads();
  if (threadIdx.x == 0) atomicAdd(lossAcc, (sh[0] + sh[1] + sh[2] + sh[3]) * scale);
}

// ================= Lovász: fill sort items =================
__global__ void k_lov_fill(const float* __restrict__ logits, const int* __restrict__ lab,
                           uint32_t* __restrict__ buf, int n, int P) {
  int i = blockIdx.x * blockDim.x + threadIdx.x;
  if (i >= P) return;
  if (i >= n) {
    for (int c = 0; c < Cc; c++) buf[(size_t)c * P + i] = 0u;
    return;
  }
  const float* l = logits + (size_t)i * Cc;
  float m = l[0];
  #pragma unroll
  for (int c = 1; c < Cc; c++) m = fmaxf(m, l[c]);
  float ex[Cc]; float se = 0.f;
  #pragma unroll
  for (int c = 0; c < Cc; c++) { ex[c] = expf(l[c] - m); se += ex[c]; }
  float inv = 1.f / se;
  int lb = lab[i];
  #pragma unroll
  for (int c = 0; c < Cc; c++) {
    float prob = ex[c] * inv;
    int fg = (c == lb) ? 1 : 0;
    float err = fg ? (1.f - prob) : prob;
    err = fmaxf(err, 0.f);
    uint32_t key = __float_as_uint(err);
    buf[(size_t)c * P + i] = (key & 0xFFFFFFFEu) | (uint32_t)fg;
  }
}

// ================= bitonic sort (descending), per-P segment =================
__global__ void k_bitonic_global(uint32_t* __restrict__ buf, int P, int j, int k) {
  int t = blockIdx.x * blockDim.x + threadIdx.x;     // one pair per thread
  int halfP = P >> 1;
  int seg = t / halfP;
  int tt  = t - seg * halfP;
  int jm1 = j - 1;
  int i = ((tt & ~jm1) << 1) | (tt & jm1);
  size_t base = (size_t)seg * P;
  uint32_t a = buf[base + i], b = buf[base + i + j];
  bool descend = ((i & k) == 0);
  if ((a < b) == descend) { buf[base + i] = b; buf[base + i + j] = a; }
}

// chunk=8192 in LDS (1024 thr x 4 pairs); stages k=kBegin..kEnd, j<=4096 fused.
__global__ void __launch_bounds__(1024)
k_bitonic_fused(uint32_t* __restrict__ buf, int P, int kBegin, int kEnd) {
  __shared__ uint32_t sh[8192];
  int t = threadIdx.x;
  size_t chunkStart = (size_t)blockIdx.x * 8192;
  int segBase = (int)(chunkStart % (size_t)P);       // segment-local chunk offset
  #pragma unroll
  for (int pp = 0; pp < 8; pp++) sh[t + pp * 1024] = buf[chunkStart + t + pp * 1024];
  for (int k = kBegin; k <= kEnd; k <<= 1) {
    int j0 = (k >> 1) < 4096 ? (k >> 1) : 4096;
    for (int j = j0; j >= 1; j >>= 1) {
      __syncthreads();
      int jm1 = j - 1;
      #pragma unroll
      for (int pp = 0; pp < 4; pp++) {
        int tt = t + pp * 1024;
        int i = ((tt & ~jm1) << 1) | (tt & jm1);
        bool descend = (((segBase + i) & k) == 0);
        uint32_t a = sh[i], b = sh[i + j];
        if ((a < b) == descend) { sh[i] = b; sh[i + j] = a; }
      }
    }
  }
  __syncthreads();
  #pragma unroll
  for (int pp = 0; pp < 8; pp++) buf[chunkStart + t + pp * 1024] = sh[t + pp * 1024];
}

// ================= Lovász: segmented scan of fg + contributions =================
__global__ void k_lov_chunksum(const uint32_t* __restrict__ buf, int* __restrict__ chunkSums) {
  int t = threadIdx.x;                                // 256
  size_t base = (size_t)blockIdx.x * 1024;
  int v = (int)(buf[base + t] & 1) + (int)(buf[base + t + 256] & 1)
        + (int)(buf[base + t + 512] & 1) + (int)(buf[base + t + 768] & 1);
  #pragma unroll
  for (int o = 32; o > 0; o >>= 1) v += __shfl_down(v, o);
  __shared__ int sh[4];
  int lane = t & 63, w = t >> 6;
  if (lane == 0) sh[w] = v;
  __syncthreads();
  if (t == 0) chunkSums[blockIdx.x] = sh[0] + sh[1] + sh[2] + sh[3];
}

__global__ void k_lov_scan(const int* __restrict__ chunkSums, int* __restrict__ chunkOffs,
                           int* __restrict__ gtsArr, int nch) {
  __shared__ int sh[128];
  int t = threadIdx.x;                                // 128
  int v = (t < nch) ? chunkSums[blockIdx.x * nch + t] : 0;
  sh[t] = v;
  __syncthreads();
  for (int o = 1; o < 128; o <<= 1) {
    int a = (t >= o) ? sh[t - o] : 0;
    __syncthreads();
    sh[t] += a;
    __syncthreads();
  }
  if (t < nch) chunkOffs[blockIdx.x * nch + t] = sh[t] - v;   // exclusive
  if (t == nch - 1) gtsArr[blockIdx.x] = sh[t];               // total fg
}

__global__ void __launch_bounds__(1024)
k_lov_contrib(const uint32_t* __restrict__ buf, const int* __restrict__ chunkOffs,
              const int* __restrict__ gtsArr, float* __restrict__ lossesC,
              int P, int nch) {
  int t = threadIdx.x;                                // 1024
  size_t g = (size_t)blockIdx.x * 1024 + t;
  int cls   = blockIdx.x / nch;
  int chunk = blockIdx.x - cls * nch;
  int iseg  = chunk * 1024 + t;
  uint32_t item = buf[g];
  int fg = item & 1;
  float e = __uint_as_float(item & 0xFFFFFFFEu);
  unsigned long long mask = __ballot(fg);
  int lane = t & 63, wave = t >> 6;
  unsigned long long le = (~0ull) >> (63 - lane);
  int wIncl = __popcll(mask & le);
  __shared__ int wsum[16];
  if (lane == 63) wsum[wave] = wIncl;                 // wave total
  __syncthreads();
  if (t == 0) { int run = 0; for (int w = 0; w < 16; w++) { int v = wsum[w]; wsum[w] = run; run += v; } }
  __syncthreads();
  float Fi  = (float)(chunkOffs[blockIdx.x] + wsum[wave] + wIncl);  // inclusive F
  float gts = (float)gtsArr[cls];
  float ip1 = (float)(iseg + 1);
  float Jc = 1.f - (gts - Fi) / (gts + ip1 - Fi);
  float Jp = 0.f;
  if (iseg > 0) {
    float Fp = Fi - (float)fg;
    Jp = 1.f - (gts - Fp) / (gts + (ip1 - 1.f) - Fp);
  }
  float contrib = e * (Jc - Jp);
  contrib = waveReduce(contrib);
  __shared__ float bs[16];
  if (lane == 0) bs[wave] = contrib;
  __syncthreads();
  if (t == 0) { float s = 0.f; for (int w = 0; w < 16; w++) s += bs[w]; atomicAdd(&lossesC[cls], s); }
}

__global__ void k_lov_combine(const float* __restrict__ lossesC, const int* __restrict__ gtsArr,
                              float* __restrict__ lossAcc, float coef) {
  float s = 0.f; int np = 0;
  for (int c = 0; c < Cc; c++) if (gtsArr[c] > 0) { s += lossesC[c]; np++; }
  atomicAdd(lossAcc, coef * s / (float)(np > 0 ? np : 1));
}

// ================= BN finalize + fuse =================
__global__ void k_colfinal(const float* __restrict__ colstats,
                           const float* __restrict__ g1, const float* __restrict__ be1,
                           const float* __restrict__ g2, const float* __restrict__ be2,
                           float* __restrict__ bnpar) {
  int j = threadIdx.x;                                // 64
  float n = (float)NIMG;
  float mu1 = colstats[j] / n;
  float var1 = colstats[64 + j] / n - mu1 * mu1;
  float a1 = g1[j] / sqrtf(var1 + BN_EPS);
  bnpar[j] = a1; bnpar[64 + j] = be1[j] - mu1 * a1;
  float mu2 = colstats[128 + j] / n;
  float var2 = colstats[192 + j] / n - mu2 * mu2;
  float a2 = g2[j] / sqrtf(var2 + BN_EPS);
  bnpar[128 + j] = a2; bnpar[192 + j] = be2[j] - mu2 * a2;
}

__global__ void k_fuse(const float* __restrict__ y1, const float* __restrict__ y2,
                       const float* __restrict__ attw, const float* __restrict__ bnpar,
                       float* __restrict__ feats, int s) {
  int g = blockIdx.x * blockDim.x + threadIdx.x;
  if (g >= NIMG * Hh) return;
  int i = g >> 6, j = g & 63;
  float z1 = fmaxf(fmaf(y1[g], bnpar[j],       bnpar[64 + j]),  0.f);
  float z2 = fmaxf(fmaf(y2[g], bnpar[128 + j], bnpar[192 + j]), 0.f);
  feats[(size_t)i * 128 + s * 64 + j] = z1 * attw[i * 2] + z2 * attw[i * 2 + 1];
}

// ================= KL(log_softmax(pts_pred) || softmax(fuse_pred)) =================
__global__ void k_kl(const float* __restrict__ fusepred, const float* __restrict__ pred3d,
                     const int* __restrict__ idx, int n, float scale, float* __restrict__ lossAcc) {
  int i = blockIdx.x * blockDim.x + threadIdx.x;
  float val = 0.f;
  if (i < n) {
    const float* f = fusepred + (size_t)i * Cc;
    const float* q = pred3d + (size_t)idx[i] * Cc;
    float mf = f[0], mq = q[0];
    #pragma unroll
    for (int c = 1; c < Cc; c++) { mf = fmaxf(mf, f[c]); mq = fmaxf(mq, q[c]); }
    float sf = 0.f, sq = 0.f;
    #pragma unroll
    for (int c = 0; c < Cc; c++) { sf += expf(f[c] - mf); sq += expf(q[c] - mq); }
    float lsf = logf(sf), lsq = logf(sq);
    #pragma unroll
    for (int c = 0; c < Cc; c++) {
      float lf = f[c] - mf - lsf;
      float pf = expf(lf);
      float lq = q[c] - mq - lsq;
      val += pf * (lf - lq);
    }
  }
  val = waveReduce(val);
  __shared__ float sh[4];
  int lane = threadIdx.x & 63, w = threadIdx.x >> 6;
  if (lane == 0) sh[w] = val;
  __syncthreads();
  if (threadIdx.x == 0) atomicAdd(lossAcc, (sh[0] + sh[1] + sh[2] + sh[3]) * scale);
}

__global__ void k_final(const float* __restrict__ lossAcc, float* __restrict__ out) {
  out[0] = lossAcc[0];
}

// ================= host-side drivers =================
static void run_sort(uint32_t* buf, int P, hipStream_t stream) {
  int total = Cc * P;
  int fusedBlocks = total / 8192;
  k_bitonic_fused<<<fusedBlocks, 1024, 0, stream>>>(buf, P, 2, 8192);
  for (int k = 16384; k <= P; k <<= 1) {
    for (int j = k >> 1; j >= 8192; j >>= 1)
      k_bitonic_global<<<(total / 2) / 256, 256, 0, stream>>>(buf, P, j, k);
    k_bitonic_fused<<<fusedBlocks, 1024, 0, stream>>>(buf, P, k, k);
  }
}

static void run_lovasz(const float* logits, const int* labels, int n, int P, float coef,
                       uint32_t* buf, int* chunkSums, int* chunkOffs,
                       float* lossesC, int* gtsArr, float* lossAcc, hipStream_t stream) {
  hipMemsetAsync(lossesC, 0, Cc * sizeof(float), stream);
  k_lov_fill<<<P / 256, 256, 0, stream>>>(logits, labels, buf, n, P);
  run_sort(buf, P, stream);
  int nch = P / 1024;
  k_lov_chunksum<<<Cc * nch, 256, 0, stream>>>(buf, chunkSums);
  k_lov_scan<<<Cc, 128, 0, stream>>>(chunkSums, chunkOffs, gtsArr, nch);
  k_lov_contrib<<<Cc * nch, 1024, 0, stream>>>(buf, chunkOffs, gtsArr, lossesC, P, nch);
  k_lov_combine<<<1, 1, 0, stream>>>(lossesC, gtsArr, lossAcc, coef);
}

extern "C" void kernel_launch(void* const* d_in, const int* in_sizes, int n_in,
                              void* d_out, int out_size, void* d_ws, size_t ws_size,
                              hipStream_t stream) {
  const float* img_feat = (const float*)d_in[0];
  const float* pts_feat = (const float*)d_in[1];
  const int* coors_inv  = (const int*)d_in[2];
  const int* labels     = (const int*)d_in[3];
  const int* img_label  = (const int*)d_in[4];
  const int* p2img      = (const int*)d_in[5];
  const float* w3a = (const float*)d_in[6];
  const float* b3a = (const float*)d_in[7];
  const float* w3b = (const float*)d_in[8];
  const float* b3b = (const float*)d_in[9];
  const float* wfa = (const float*)d_in[10];
  const float* bfa = (const float*)d_in[11];
  const float* wfb = (const float*)d_in[12];
  const float* bfb = (const float*)d_in[13];
  const float* fc1w = (const float*)d_in[14];
  const float* fc1b = (const float*)d_in[15];
  const float* fc2w = (const float*)d_in[16];
  const float* fc2b = (const float*)d_in[17];
  const float* fc3w = (const float*)d_in[18];
  const float* fc3b = (const float*)d_in[19];
  const float* c1w  = (const float*)d_in[20];
  const float* c1b  = (const float*)d_in[21];
  const float* bn1g = (const float*)d_in[22];
  const float* bn1b = (const float*)d_in[23];
  const float* c2w  = (const float*)d_in[24];
  const float* c2b  = (const float*)d_in[25];
  const float* bn2g = (const float*)d_in[26];
  const float* bn2b = (const float*)d_in[27];
  const float* clw1 = (const float*)d_in[28];
  const float* clb1 = (const float*)d_in[29];
  const float* clw2 = (const float*)d_in[30];
  const float* clb2 = (const float*)d_in[31];
  (void)in_sizes; (void)n_in; (void)out_size; (void)ws_size;

  // ---- workspace layout (time-disjoint overlays; ~75 MB total) ----
  char* ws = (char*)d_ws;
  size_t off = 0;
  auto alloc = [&](size_t bytes) { void* p = ws + off; off += (bytes + 255) & ~(size_t)255; return p; };
  float* feats  = (float*)alloc((size_t)NIMG * 128 * 4);   // persistent (concat of fuse[s])
  float* pred3d = (float*)alloc((size_t)NV * Cc * 4);
  int*   voxlab = (int*)  alloc((size_t)NV * 4);
  int*   idx    = (int*)  alloc((size_t)NIMG * 4);
  // regionA: y1+y2 (live gemm..fuse)  OVERLAYS  sortbuf (live lovasz only)
  char* regionA = (char*)alloc((size_t)NIMG * Hh * 4 * 2);  // 30.72MB >= 20*P3D*4
  float* y1 = (float*)regionA;
  float* y2 = (float*)(regionA + (size_t)NIMG * Hh * 4);
  uint32_t* sortbuf = (uint32_t*)regionA;
  // regionB: counts (live early)  OVERLAYS  attw+fusepred (live late)
  char* regionB = (char*)alloc((size_t)NV * Cc * 4);        // 6.4MB >= 0.48+4.8MB
  int*   counts   = (int*)regionB;
  float* attw     = (float*)regionB;
  float* fusepred = (float*)(regionB + (size_t)NIMG * 2 * 4);
  int* chunkSums = (int*)alloc(Cc * 128 * 4);
  int* chunkOffs = (int*)alloc(Cc * 128 * 4);
  float* statsF  = (float*)alloc(4096);
  float* lossAcc  = statsF;             // [0]
  float* lossesC  = statsF + 1;         // [1..21)
  int*   gtsArr   = (int*)(statsF + 21);// 20 ints
  float* colstats = statsF + 64;        // 256 floats
  float* bnpar    = statsF + 320;       // 256 floats

  hipMemsetAsync(statsF, 0, 4096, stream);

  for (int s = 0; s < 2; s++) {
    const float* pf_s = pts_feat + (size_t)s * NV * Hh;
    const float* if_s = img_feat + (size_t)s * NIMG * Hh;
    const int*   ci_s = coors_inv + (size_t)s * NPT;
    hipMemsetAsync(counts, 0, (size_t)NV * Cc * 4, stream);
    hipMemsetAsync(colstats, 0, 256 * 4, stream);
    k_idx<<<(NIMG + 255) / 256, 256, 0, stream>>>(ci_s, p2img, idx);
    // pred3d = mlp2(pts_feat[s])
    k_mlp2t<64, 64><<<NV / 64, 256, 0, stream>>>(pf_s, Hh, 0, NV,
        w3a + s * 64 * 128, b3a + s * 128, w3b + s * 128 * Cc, b3b + s * Cc, pred3d);
    k_counts<<<(NPT + 255) / 256, 256, 0, stream>>>(ci_s, labels, counts);
    k_voxlab<<<(NV + 255) / 256, 256, 0, stream>>>(counts, voxlab);
    // seg_loss(pred3d, vox_lab), coef 1
    k_ce<<<(NV + 255) / 256, 256, 0, stream>>>(pred3d, voxlab, NV, 1.0f / NV, lossAcc);
    run_lovasz(pred3d, voxlab, NV, P3D, 1.0f, sortbuf, chunkSums, chunkOffs,
               lossesC, gtsArr, lossAcc, stream);
    // fused gather + conv GEMMs + BN stats + attention
    k_gemm_att<<<(NIMG + 63) / 64, 256, 0, stream>>>(pf_s, idx, if_s,
        c1w + s * 4096, c1b + s * 64, c2w + s * 4096, c2b + s * 64,
        fc1w + s * 64 * 16, fc1b + s * 16, fc2w + s * 64 * 16, fc2b + s * 16,
        fc3w + s * 64, fc3b + s * 2, y1, y2, attw, colstats);
    k_colfinal<<<1, 64, 0, stream>>>(colstats, bn1g + s * 64, bn1b + s * 64,
                                     bn2g + s * 64, bn2b + s * 64, bnpar);
    k_fuse<<<(NIMG * Hh + 255) / 256, 256, 0, stream>>>(y1, y2, attw, bnpar, feats, s);
    // fuse_pred = mlp2(fuse)
    k_mlp2t<64, 64><<<(NIMG + 63) / 64, 256, 0, stream>>>(feats, 128, s * 64, NIMG,
        wfa + s * 64 * 128, bfa + s * 128, wfb + s * 128 * Cc, bfb + s * Cc, fusepred);
    // seg_loss(fuse_pred, img_label) * 1/S
    k_ce<<<(NIMG + 255) / 256, 256, 0, stream>>>(fusepred, img_label, NIMG, 0.5f / NIMG, lossAcc);
    run_lovasz(fusepred, img_label, NIMG, P2D, 0.5f, sortbuf, chunkSums, chunkOffs,
               lossesC, gtsArr, lossAcc, stream);
    // KL * 0.05/S, mean over NIMG*C elements
    k_kl<<<(NIMG + 255) / 256, 256, 0, stream>>>(fusepred, pred3d, idx, NIMG,
        0.025f / ((float)NIMG * Cc), lossAcc);
  }
  // final classifier on concat feats
  k_mlp2t<32, 128><<<(NIMG + 31) / 32, 256, 0, stream>>>(feats, 128, 0, NIMG,
      clw1, clb1, clw2, clb2, fusepred);
  k_ce<<<(NIMG + 255) / 256, 256, 0, stream>>>(fusepred, img_label, NIMG, 1.0f / NIMG, lossAcc);
  run_lovasz(fusepred, img_label, NIMG, P2D, 1.0f, sortbuf, chunkSums, chunkOffs,
             lossesC, gtsArr, lossAcc, stream);
  k_final<<<1, 1, 0, stream>>>(lossAcc, (float*)d_out);
}